// Round 1
// baseline (75.958 us; speedup 1.0000x reference)
//
#include <hip/hip_runtime.h>
#include <hip/hip_bf16.h>
#include <math.h>

// Problem constants (from reference)
constexpr int B = 64;
constexpr int L = 2048;
constexpr int D = 1024;
constexpr int P = 512;
constexpr int C = 32;

constexpr int NT = 512;   // threads per block (8 waves)
constexpr int NG = 4;     // reduction groups along d/q
constexpr int TP = NT / NG; // 128 threads per group; each owns 4 consecutive p

__global__ __launch_bounds__(NT) void relpred_fused(
    const float* __restrict__ enc,      // B x L x D
    const int*   __restrict__ prep_idx, // B x 1
    const float* __restrict__ Wh,       // D x P
    const float* __restrict__ Wp,       // D x P
    const float* __restrict__ Wc,       // D x P
    const float* __restrict__ Whid,     // P x P
    const float* __restrict__ Wsc,      // P x C
    float*       __restrict__ out)      // B x C
{
    const int b   = blockIdx.x;
    const int tid = threadIdx.x;

    __shared__ float s_enc[3 * D];      // 12 KB: head|prep|child rows
    __shared__ float s_part[NG][P];     // 8 KB partials
    __shared__ float s_comp[P];         // 2 KB composed vector
    __shared__ float s_part3[16][C];    // 2 KB stage-3 partials

    // ---- gather 3 rows (prep-1, prep, prep+1) into LDS ----
    const int prep = prep_idx[b];
    const float4* src = reinterpret_cast<const float4*>(
        enc + ((size_t)b * L + (size_t)(prep - 1)) * D);
    float4* dst = reinterpret_cast<float4*>(s_enc);
    #pragma unroll
    for (int i = tid; i < 3 * D / 4; i += NT) dst[i] = src[i];
    __syncthreads();

    const int g  = tid / TP;   // 0..3  (d-range group)
    const int t  = tid % TP;   // 0..127
    const int p4 = t * 4;      // this thread's 4 output columns

    // ---- stage 1: composed = tanh(h@Wh + p@Wp + c@Wc) ----
    {
        float4 acc = make_float4(0.f, 0.f, 0.f, 0.f);
        const int d0 = g * (D / NG);
        const int d1 = d0 + (D / NG);
        #pragma unroll 4
        for (int d = d0; d < d1; ++d) {
            const float h  = s_enc[d];
            const float pr = s_enc[D + d];
            const float ch = s_enc[2 * D + d];
            const float4 wh = *reinterpret_cast<const float4*>(&Wh[(size_t)d * P + p4]);
            const float4 wp = *reinterpret_cast<const float4*>(&Wp[(size_t)d * P + p4]);
            const float4 wc = *reinterpret_cast<const float4*>(&Wc[(size_t)d * P + p4]);
            acc.x += h * wh.x + pr * wp.x + ch * wc.x;
            acc.y += h * wh.y + pr * wp.y + ch * wc.y;
            acc.z += h * wh.z + pr * wp.z + ch * wc.z;
            acc.w += h * wh.w + pr * wp.w + ch * wc.w;
        }
        *reinterpret_cast<float4*>(&s_part[g][p4]) = acc;
    }
    __syncthreads();
    {   // reduce groups, tanh; thread tid owns p = tid
        float v = s_part[0][tid] + s_part[1][tid] + s_part[2][tid] + s_part[3][tid];
        s_comp[tid] = tanhf(v);
    }
    __syncthreads();

    // ---- stage 2: composed = tanh(composed @ Whid) ----
    {
        float4 acc = make_float4(0.f, 0.f, 0.f, 0.f);
        const int q0 = g * (P / NG);
        const int q1 = q0 + (P / NG);
        #pragma unroll 4
        for (int q = q0; q < q1; ++q) {
            const float cv = s_comp[q];
            const float4 w = *reinterpret_cast<const float4*>(&Whid[(size_t)q * P + p4]);
            acc.x += cv * w.x;
            acc.y += cv * w.y;
            acc.z += cv * w.z;
            acc.w += cv * w.w;
        }
        *reinterpret_cast<float4*>(&s_part[g][p4]) = acc;
    }
    __syncthreads();
    {   // reduce, tanh, store composed2 (reuse s_comp AFTER all reads done)
        float v = s_part[0][tid] + s_part[1][tid] + s_part[2][tid] + s_part[3][tid];
        __syncthreads();            // make sure stage-2 reads of s_comp are complete
        s_comp[tid] = tanhf(v);
    }
    __syncthreads();

    // ---- stage 3: scores = composed2 @ Wsc, softmax over C=32 ----
    {
        const int c   = tid & (C - 1);  // 0..31
        const int grp = tid >> 5;       // 0..15, each covers 32 p's
        float partial = 0.f;
        #pragma unroll
        for (int k = 0; k < P / 16; ++k) {
            const int p = grp * (P / 16) + k;
            partial += s_comp[p] * Wsc[(size_t)p * C + c];
        }
        s_part3[grp][c] = partial;
    }
    __syncthreads();

    if (tid < C) {
        float score = 0.f;
        #pragma unroll
        for (int gq = 0; gq < 16; ++gq) score += s_part3[gq][tid];
        // softmax across lanes 0..31 (xor patterns stay within the low 32 lanes)
        float m = score;
        #pragma unroll
        for (int off = 16; off; off >>= 1) m = fmaxf(m, __shfl_xor(m, off));
        const float e = expf(score - m);
        float s = e;
        #pragma unroll
        for (int off = 16; off; off >>= 1) s += __shfl_xor(s, off);
        out[b * C + tid] = e / s;
    }
}

extern "C" void kernel_launch(void* const* d_in, const int* in_sizes, int n_in,
                              void* d_out, int out_size, void* d_ws, size_t ws_size,
                              hipStream_t stream) {
    const float* enc      = (const float*)d_in[0];
    const int*   prep_idx = (const int*)  d_in[1];
    const float* Wh       = (const float*)d_in[2];
    const float* Wp       = (const float*)d_in[3];
    const float* Wc       = (const float*)d_in[4];
    const float* Whid     = (const float*)d_in[5];
    const float* Wsc      = (const float*)d_in[6];
    float*       out      = (float*)d_out;

    relpred_fused<<<B, NT, 0, stream>>>(enc, prep_idx, Wh, Wp, Wc, Whid, Wsc, out);
}

// Round 2
// 44.904 us; speedup vs baseline: 1.6916x; 1.6916x over previous
//
#include <hip/hip_runtime.h>
#include <math.h>

constexpr int B = 64, L = 2048, D = 1024, P = 512, C = 32;

// ===================== Stage 1 =====================
// partial1[kc][b][p] = X[b, k-chunk] dot W1[k-chunk, p]
// X = concat(head,prep,child) (64 x 3072), W1 = [Wh;Wp;Wc] (3072 x 512)
// grid (4 col-tiles of 128, NK1 = 3072/CH1 chunks). CH1 divides 1024.
template<int CH1>
__global__ __launch_bounds__(256) void s1_kernel(
    const float* __restrict__ enc, const int* __restrict__ prep_idx,
    const float* __restrict__ Wh, const float* __restrict__ Wp,
    const float* __restrict__ Wc, float* __restrict__ partial1)
{
    const int ct = blockIdx.x;                 // 0..3 (128 cols each)
    const int kc = blockIdx.y;                 // 0..NK1-1
    constexpr int CPM = 1024 / CH1;            // chunks per source matrix
    const int m    = kc / CPM;                 // 0=head,1=prep,2=child
    const int koff = (kc % CPM) * CH1;
    const float* Wm = (m == 0) ? Wh : (m == 1) ? Wp : Wc;

    __shared__ float Xt[CH1][68];              // transposed X chunk (+pad)
    __shared__ float Wl[CH1][128];

    const int tid = threadIdx.x;

    // stage W: CH1 rows x 128 cols (coalesced float4)
    for (int i = tid; i < CH1 * 32; i += 256) {
        const int r = i >> 5, c4 = (i & 31) * 4;
        *(float4*)&Wl[r][c4] =
            *(const float4*)&Wm[(size_t)(koff + r) * P + ct * 128 + c4];
    }
    // stage X (gather 3 rows around prep), transposed into Xt[k][b]
    constexpr int QPB = CH1 / 4;               // float4 per batch row
    for (int i = tid; i < 64 * QPB; i += 256) {
        const int b = i / QPB, q = i % QPB;
        const int row = prep_idx[b] + m - 1;
        const float4 v = *(const float4*)&enc[((size_t)b * L + row) * D + koff + q * 4];
        Xt[q*4+0][b] = v.x; Xt[q*4+1][b] = v.y;
        Xt[q*4+2][b] = v.z; Xt[q*4+3][b] = v.w;
    }
    __syncthreads();

    const int ty = tid >> 4, tx = tid & 15;    // ty: 16 batch groups, tx: 16 col groups
    float acc[4][8];
    #pragma unroll
    for (int i = 0; i < 4; ++i)
        #pragma unroll
        for (int j = 0; j < 8; ++j) acc[i][j] = 0.f;

    #pragma unroll 4
    for (int k = 0; k < CH1; ++k) {
        const float4 xv = *(float4*)&Xt[k][ty * 4];
        const float4 w0 = *(float4*)&Wl[k][tx * 8];
        const float4 w1 = *(float4*)&Wl[k][tx * 8 + 4];
        const float xs[4] = {xv.x, xv.y, xv.z, xv.w};
        const float ws8[8] = {w0.x, w0.y, w0.z, w0.w, w1.x, w1.y, w1.z, w1.w};
        #pragma unroll
        for (int i = 0; i < 4; ++i)
            #pragma unroll
            for (int j = 0; j < 8; ++j) acc[i][j] += xs[i] * ws8[j];
    }

    #pragma unroll
    for (int i = 0; i < 4; ++i) {
        const int b = ty * 4 + i;
        const size_t base = ((size_t)kc * 64 + b) * P + ct * 128 + tx * 8;
        float4 o0 = make_float4(acc[i][0], acc[i][1], acc[i][2], acc[i][3]);
        float4 o1 = make_float4(acc[i][4], acc[i][5], acc[i][6], acc[i][7]);
        *(float4*)&partial1[base]     = o0;
        *(float4*)&partial1[base + 4] = o1;
    }
}

// ===================== Reduce 1 =====================
__global__ __launch_bounds__(256) void r1_kernel(
    const float* __restrict__ partial1, float* __restrict__ C1, int NK)
{
    const int o = blockIdx.x * 256 + threadIdx.x;   // 64*512 outputs
    float s = 0.f;
    for (int kc = 0; kc < NK; ++kc) s += partial1[(size_t)kc * (64 * P) + o];
    C1[o] = tanhf(s);
}

// ===================== Stage 2 =====================
// partial2[kc][b][q] = C1[b, k-chunk] dot Whid[k-chunk, q]; grid (8, 16), chunk 32
__global__ __launch_bounds__(256) void s2_kernel(
    const float* __restrict__ C1, const float* __restrict__ Whid,
    float* __restrict__ partial2)
{
    const int ct = blockIdx.x;            // 0..7 (64 cols each)
    const int kc = blockIdx.y;            // 0..15
    const int koff = kc * 32;

    __shared__ float Ct[32][68];
    __shared__ float Wl[32][64];

    const int tid = threadIdx.x;
    // stage Whid chunk: 32 x 64
    for (int i = tid; i < 32 * 16; i += 256) {
        const int r = i >> 4, c4 = (i & 15) * 4;
        *(float4*)&Wl[r][c4] =
            *(const float4*)&Whid[(size_t)(koff + r) * P + ct * 64 + c4];
    }
    // stage C1 chunk transposed: Ct[k][b]
    for (int i = tid; i < 64 * 8; i += 256) {
        const int b = i >> 3, q = i & 7;
        const float4 v = *(const float4*)&C1[(size_t)b * P + koff + q * 4];
        Ct[q*4+0][b] = v.x; Ct[q*4+1][b] = v.y;
        Ct[q*4+2][b] = v.z; Ct[q*4+3][b] = v.w;
    }
    __syncthreads();

    const int ty = tid >> 4, tx = tid & 15;
    float acc[4][4];
    #pragma unroll
    for (int i = 0; i < 4; ++i)
        #pragma unroll
        for (int j = 0; j < 4; ++j) acc[i][j] = 0.f;

    #pragma unroll 4
    for (int k = 0; k < 32; ++k) {
        const float4 xv = *(float4*)&Ct[k][ty * 4];
        const float4 wv = *(float4*)&Wl[k][tx * 4];
        const float xs[4] = {xv.x, xv.y, xv.z, xv.w};
        const float wv4[4] = {wv.x, wv.y, wv.z, wv.w};
        #pragma unroll
        for (int i = 0; i < 4; ++i)
            #pragma unroll
            for (int j = 0; j < 4; ++j) acc[i][j] += xs[i] * wv4[j];
    }

    #pragma unroll
    for (int i = 0; i < 4; ++i) {
        const int b = ty * 4 + i;
        const size_t base = ((size_t)kc * 64 + b) * P + ct * 64 + tx * 4;
        *(float4*)&partial2[base] =
            make_float4(acc[i][0], acc[i][1], acc[i][2], acc[i][3]);
    }
}

// ===================== Stage 3 =====================
// per-batch: c2 = tanh(sum_k partial2); scores = c2 @ scorer; softmax
__global__ __launch_bounds__(256) void s3_kernel(
    const float* __restrict__ partial2, const float* __restrict__ scorer,
    float* __restrict__ out, int NK2)
{
    const int b   = blockIdx.x;
    const int tid = threadIdx.x;

    __shared__ float c2[P];
    __shared__ float s_part[8][C];

    #pragma unroll
    for (int pp = tid; pp < P; pp += 256) {
        float s = 0.f;
        for (int kc = 0; kc < NK2; ++kc)
            s += partial2[((size_t)kc * 64 + b) * P + pp];
        c2[pp] = tanhf(s);
    }
    __syncthreads();

    const int c = tid & (C - 1);     // 0..31
    const int g = tid >> 5;          // 0..7, each covers 64 p
    float partial = 0.f;
    #pragma unroll
    for (int k = 0; k < P / 8; ++k) {
        const int p = g * (P / 8) + k;
        partial += c2[p] * scorer[(size_t)p * C + c];
    }
    s_part[g][c] = partial;
    __syncthreads();

    if (tid < C) {
        float score = 0.f;
        #pragma unroll
        for (int gq = 0; gq < 8; ++gq) score += s_part[gq][tid];
        float m = score;
        #pragma unroll
        for (int off = 16; off; off >>= 1) m = fmaxf(m, __shfl_xor(m, off));
        const float e = expf(score - m);
        float s = e;
        #pragma unroll
        for (int off = 16; off; off >>= 1) s += __shfl_xor(s, off);
        out[b * C + tid] = e / s;
    }
}

extern "C" void kernel_launch(void* const* d_in, const int* in_sizes, int n_in,
                              void* d_out, int out_size, void* d_ws, size_t ws_size,
                              hipStream_t stream) {
    const float* enc      = (const float*)d_in[0];
    const int*   prep_idx = (const int*)  d_in[1];
    const float* Wh       = (const float*)d_in[2];
    const float* Wp       = (const float*)d_in[3];
    const float* Wc       = (const float*)d_in[4];
    const float* Whid     = (const float*)d_in[5];
    const float* Wsc      = (const float*)d_in[6];
    float*       out      = (float*)d_out;
    float*       wsf      = (float*)d_ws;

    // ws layout: [partial1 (NK1*64*512)] [C1 (64*512)]; partial2 reuses partial1.
    const size_t need64 = (size_t)(48 * 64 * 512 + 64 * 512) * 4;
    const bool big = ws_size >= need64;
    const int NK1 = big ? 48 : 24;             // CH1 = 64 or 128

    float* partial1 = wsf;
    float* C1       = wsf + (size_t)NK1 * 64 * P;
    float* partial2 = wsf;                      // reuse (partial1 dead after r1)

    if (big) {
        s1_kernel<64><<<dim3(4, 48), 256, 0, stream>>>(enc, prep_idx, Wh, Wp, Wc, partial1);
    } else {
        s1_kernel<128><<<dim3(4, 24), 256, 0, stream>>>(enc, prep_idx, Wh, Wp, Wc, partial1);
    }
    r1_kernel<<<128, 256, 0, stream>>>(partial1, C1, NK1);
    s2_kernel<<<dim3(8, 16), 256, 0, stream>>>(C1, Whid, partial2);
    s3_kernel<<<64, 256, 0, stream>>>(partial2, Wsc, out, 16);
}